// Round 14
// baseline (1259.923 us; speedup 1.0000x reference)
//
#include <hip/hip_runtime.h>

#define NV 20000
#define NNZE 6400000
#define KD 1280          // K = B * C_IN * R_IN
#define ND 512           // C_OUT * R_OUT
#define MROWS 20000
#define NR 1600000       // NV * 80 agg rows
#define RPB 256          // rows per bucket
#define NB 6250          // NR / RPB buckets
#define NREP 16          // replica streams per bucket (kills fetch-add chains)
#define NCTR (NB * NREP) // 100000 logical counters
#define NBLK 49          // ceil(NCTR / 2048) scan blocks

typedef __attribute__((ext_vector_type(8))) short short8;
typedef __attribute__((ext_vector_type(4))) float f32x4;

// exact RNE f32 -> bf16 (finite inputs)
static __device__ __forceinline__ unsigned short f2bf(float f) {
    unsigned int u = __float_as_uint(f);
    return (unsigned short)((u + 0x7FFFu + ((u >> 16) & 1u)) >> 16);
}

__global__ __launch_bounds__(256) void zero_u32(unsigned int* __restrict__ p, int n) {
    int i = blockIdx.x * 256 + threadIdx.x;
    if (i < n) p[i] = 0u;
}

// lwT[n][k] (bf16, n-major) where lw[k][n] = weights[o*KD + src], n = o*16+j
__global__ __launch_bounds__(256) void build_lwT_kernel(
        const float* __restrict__ w, unsigned short* __restrict__ lwT) {
    int idx = blockIdx.x * 256 + threadIdx.x;           // < 512*1280
    int n = idx / KD;
    int k = idx - n * KD;
    int o = n >> 4, j = n & 15;
    int ci = k / 80;
    int i  = k - ci * 80;
    int t  = i / 5, p = i - t * 5;
    int src = ci * 80 + ((t + j) & 15) * 5 + p;
    lwT[idx] = f2bf(w[o * KD + src]);
}

// count edges per (bucket, replica); non-returning atomics pipeline at L2
__global__ __launch_bounds__(256) void hist_kernel(
        const int* __restrict__ rows, unsigned int* __restrict__ A) {
    int e = blockIdx.x * 256 + threadIdx.x;             // grid exact = NNZE
    atomicAdd(&A[(rows[e] >> 8) * NREP + (e & (NREP - 1))], 1u);
}

// in-place block-local exclusive scan of A[NCTR]; bsum[b] = block total
__global__ __launch_bounds__(256) void scan1_kernel(
        unsigned int* __restrict__ A, unsigned int* __restrict__ bsum) {
    __shared__ unsigned int sh[256];
    int tid  = threadIdx.x;
    int base = blockIdx.x * 2048 + tid * 8;
    unsigned int v[8];
    unsigned int run = 0;
#pragma unroll
    for (int q = 0; q < 8; q++) {
        unsigned int t = (base + q < NCTR) ? A[base + q] : 0u;
        v[q] = run;                 // thread-local exclusive
        run += t;
    }
    sh[tid] = run;
    __syncthreads();
    unsigned int own = run;
    for (int ofs = 1; ofs < 256; ofs <<= 1) {           // Hillis-Steele inclusive
        unsigned int t = (tid >= ofs) ? sh[tid - ofs] : 0u;
        __syncthreads();
        sh[tid] += t;
        __syncthreads();
    }
    unsigned int excl = sh[tid] - own;
#pragma unroll
    for (int q = 0; q < 8; q++)
        if (base + q < NCTR) A[base + q] = excl + v[q];
    if (tid == 255) bsum[blockIdx.x] = sh[255];
}

// exclusive scan of bsum[NBLK] in place (single block)
__global__ __launch_bounds__(64) void scan2_kernel(unsigned int* __restrict__ bsum) {
    __shared__ unsigned int sh[64];
    int tid = threadIdx.x;
    unsigned int v = (tid < NBLK) ? bsum[tid] : 0u;
    sh[tid] = v;
    __syncthreads();
    for (int ofs = 1; ofs < 64; ofs <<= 1) {
        unsigned int t = (tid >= ofs) ? sh[tid - ofs] : 0u;
        __syncthreads();
        sh[tid] += t;
        __syncthreads();
    }
    if (tid < NBLK) bsum[tid] = sh[tid] - v;            // exclusive
}

// scatter edges into (bucket,replica)-sorted order. Chain depth per counter =
// ~64; sub-streams concatenate so bucket stays contiguous.
// entry = (val_bits, col<<8 | row&255). After: A[i] = local inclusive prefix.
__global__ __launch_bounds__(256) void reorder_kernel(
        const int* __restrict__ rows, const float* __restrict__ vals,
        const int* __restrict__ cols, unsigned int* __restrict__ A,
        const unsigned int* __restrict__ bsum, uint2* __restrict__ entries) {
    int e = blockIdx.x * 256 + threadIdx.x;             // grid exact = NNZE
    int r = rows[e];
    int i = (r >> 8) * NREP + (e & (NREP - 1));
    unsigned int pos = bsum[i >> 11] + atomicAdd(&A[i], 1u);
    entries[pos] = make_uint2(__float_as_uint(vals[e]),
                              ((unsigned int)cols[e] << 8) | (unsigned int)(r & 255));
}

// one block per bucket; ONE EDGE PER LANE (R12 lesson: 16-lanes-per-edge gave
// only 4 edges in flight per wave; per-lane edges give 64 -> 16x MLP for free).
// LDS transposed: lacc[ch][256] so atomic bank = lr&31 (random rows spread all
// 32 banks) and channel index is compile-time (no scratch, rule #20).
__global__ __launch_bounds__(256) void accum_lane_kernel(
        const uint2* __restrict__ entries, const unsigned int* __restrict__ A,
        const unsigned int* __restrict__ bsum, const float* __restrict__ x,
        unsigned short* __restrict__ agg) {
    __shared__ float lacc[16 * RPB];                    // [ch][row], 16 KB
    int tid = threadIdx.x;
    int b   = blockIdx.x;
#pragma unroll
    for (int q = 0; q < 4; q++)
        *(f32x4*)&lacc[(q * 256 + tid) * 4] = (f32x4){0.f, 0.f, 0.f, 0.f};
    __syncthreads();

    int i0 = b * NREP;
    int i1 = i0 + NREP - 1;
    unsigned int start = (i0 > 0) ? (A[i0 - 1] + bsum[(i0 - 1) >> 11]) : 0u;
    unsigned int end   = A[i1] + bsum[i1 >> 11];

    for (unsigned int p = start + tid; p < end; p += 256) {
        uint2 s = entries[p];                     // coalesced: 64 lanes x 8B
        float v = __uint_as_float(s.x);
        int col = (int)(s.y >> 8);
        int lr  = (int)(s.y & 255);
        const f32x4* xr = (const f32x4*)(x + ((size_t)col << 4));  // 64B aligned
        f32x4 x0 = xr[0], x1 = xr[1], x2 = xr[2], x3 = xr[3];      // 4 indep loads
        atomicAdd(&lacc[ 0 * 256 + lr], v * x0.x);
        atomicAdd(&lacc[ 1 * 256 + lr], v * x0.y);
        atomicAdd(&lacc[ 2 * 256 + lr], v * x0.z);
        atomicAdd(&lacc[ 3 * 256 + lr], v * x0.w);
        atomicAdd(&lacc[ 4 * 256 + lr], v * x1.x);
        atomicAdd(&lacc[ 5 * 256 + lr], v * x1.y);
        atomicAdd(&lacc[ 6 * 256 + lr], v * x1.z);
        atomicAdd(&lacc[ 7 * 256 + lr], v * x1.w);
        atomicAdd(&lacc[ 8 * 256 + lr], v * x2.x);
        atomicAdd(&lacc[ 9 * 256 + lr], v * x2.y);
        atomicAdd(&lacc[10 * 256 + lr], v * x2.z);
        atomicAdd(&lacc[11 * 256 + lr], v * x2.w);
        atomicAdd(&lacc[12 * 256 + lr], v * x3.x);
        atomicAdd(&lacc[13 * 256 + lr], v * x3.y);
        atomicAdd(&lacc[14 * 256 + lr], v * x3.z);
        atomicAdd(&lacc[15 * 256 + lr], v * x3.w);
    }
    __syncthreads();

    // writeout: thread t owns row t. Read lacc[ch][t] (consecutive t -> no
    // bank conflict per compile-time ch), emit 16 bf16 = 2 x 16B stores.
    int lr = tid;
    float r0 = lacc[ 0 * 256 + lr], r1 = lacc[ 1 * 256 + lr];
    float r2 = lacc[ 2 * 256 + lr], r3 = lacc[ 3 * 256 + lr];
    float r4 = lacc[ 4 * 256 + lr], r5 = lacc[ 5 * 256 + lr];
    float r6 = lacc[ 6 * 256 + lr], r7 = lacc[ 7 * 256 + lr];
    float r8 = lacc[ 8 * 256 + lr], r9 = lacc[ 9 * 256 + lr];
    float rA = lacc[10 * 256 + lr], rB = lacc[11 * 256 + lr];
    float rC = lacc[12 * 256 + lr], rD = lacc[13 * 256 + lr];
    float rE = lacc[14 * 256 + lr], rF = lacc[15 * 256 + lr];
    short8 o0, o1;
    o0[0] = (short)f2bf(r0); o0[1] = (short)f2bf(r1);
    o0[2] = (short)f2bf(r2); o0[3] = (short)f2bf(r3);
    o0[4] = (short)f2bf(r4); o0[5] = (short)f2bf(r5);
    o0[6] = (short)f2bf(r6); o0[7] = (short)f2bf(r7);
    o1[0] = (short)f2bf(r8); o1[1] = (short)f2bf(r9);
    o1[2] = (short)f2bf(rA); o1[3] = (short)f2bf(rB);
    o1[4] = (short)f2bf(rC); o1[5] = (short)f2bf(rD);
    o1[6] = (short)f2bf(rE); o1[7] = (short)f2bf(rF);
    unsigned short* dst = agg + (size_t)b * (RPB * 16) + (size_t)lr * 16;
    *(short8*)dst       = o0;
    *(short8*)(dst + 8) = o1;
}

// C[M][512] = Abf[M][1280] * lwT^T ; bf16 MFMA 16x16x32, 128x128 tile, BK=64.
// Both operands staged via global_load_lds (linear LDS dest, inverse-pre-swizzled
// global source, swizzle cb ^= (row&7)<<4). A rows >= MROWS clamp to MROWS-1
// (epilogue masks those stores).
__global__ __launch_bounds__(256) void gemm_kernel(
        const unsigned short* __restrict__ Abf, const unsigned short* __restrict__ lwT,
        float* __restrict__ C) {
    __shared__ __align__(16) char lds[2 * 128 * 64 * 2];   // As 16KB | Bs 16KB
    char* As = lds;
    char* Bs = lds + 16384;

    int tid  = threadIdx.x;
    int lane = tid & 63;
    int wid  = tid >> 6;
    int wr = wid >> 1, wc = wid & 1;       // 2x2 waves, 64x64 each
    int m0 = blockIdx.x * 128;
    int n0 = blockIdx.y * 128;
    int l15 = lane & 15;
    int l4  = lane >> 4;

    f32x4 acc[4][4] = {};

    for (int k0 = 0; k0 < KD; k0 += 64) {
#pragma unroll
        for (int rd = 0; rd < 4; rd++) {
            int idx  = rd * 256 + tid;
            int trow = idx >> 3;                  // 0..127 (LDS row)
            int cb   = (idx & 7) * 16;            // byte in 128B row slice
            int swz  = cb ^ ((trow & 7) << 4);
            int gr   = m0 + trow;
            if (gr > MROWS - 1) gr = MROWS - 1;   // clamp; stores masked later
            size_t asrc = (size_t)gr * (KD * 2) + (size_t)(k0 * 2) + swz;
            __builtin_amdgcn_global_load_lds(
                (const __attribute__((address_space(1))) void*)((const char*)Abf + asrc),
                (__attribute__((address_space(3))) void*)(As + rd * 4096 + wid * 1024),
                16, 0, 0);
            size_t bsrc = (size_t)(n0 + trow) * (KD * 2) + (size_t)(k0 * 2) + swz;
            __builtin_amdgcn_global_load_lds(
                (const __attribute__((address_space(1))) void*)((const char*)lwT + bsrc),
                (__attribute__((address_space(3))) void*)(Bs + rd * 4096 + wid * 1024),
                16, 0, 0);
        }

        __syncthreads();   // compiler drains vmcnt before barrier (proven R4)

#pragma unroll
        for (int ks = 0; ks < 2; ks++) {
            short8 af[4], bf[4];
            int kb = ks * 64 + l4 * 16;
#pragma unroll
            for (int m = 0; m < 4; m++) {
                int r = wr * 64 + m * 16 + l15;
                af[m] = *(const short8*)(As + r * 128 + (kb ^ ((r & 7) << 4)));
            }
#pragma unroll
            for (int n = 0; n < 4; n++) {
                int r = wc * 64 + n * 16 + l15;
                bf[n] = *(const short8*)(Bs + r * 128 + (kb ^ ((r & 7) << 4)));
            }
#pragma unroll
            for (int m = 0; m < 4; m++)
#pragma unroll
                for (int n = 0; n < 4; n++)
                    acc[m][n] = __builtin_amdgcn_mfma_f32_16x16x32_bf16(
                                    af[m], bf[n], acc[m][n], 0, 0, 0);
        }

        __syncthreads();
    }

    // epilogue: D col = lane&15, row = (lane>>4)*4 + reg
#pragma unroll
    for (int m = 0; m < 4; m++) {
        int row_b = m0 + wr * 64 + m * 16 + l4 * 4;
#pragma unroll
        for (int n = 0; n < 4; n++) {
            int col = n0 + wc * 64 + n * 16 + l15;
#pragma unroll
            for (int r = 0; r < 4; r++) {
                int row = row_b + r;
                if (row < MROWS) C[(size_t)row * ND + col] = acc[m][n][r];
            }
        }
    }
}

extern "C" void kernel_launch(void* const* d_in, const int* in_sizes, int n_in,
                              void* d_out, int out_size, void* d_ws, size_t ws_size,
                              hipStream_t stream) {
    const float* x         = (const float*)d_in[0];
    const float* weights   = (const float*)d_in[1];
    const float* conn_vals = (const float*)d_in[2];
    const int*   conn_rows = (const int*)d_in[3];
    const int*   conn_cols = (const int*)d_in[4];
    float* out = (float*)d_out;

    // ws layout (104.11 MB total < 104.20 MB proven in R4; all 16B-aligned):
    char* ws = (char*)d_ws;
    unsigned short* agg     = (unsigned short*)ws;               // 51,200,000 B
    uint2*          entries = (uint2*)(ws + 51200000);           // 51,200,000 B
    unsigned int*   A       = (unsigned int*)(ws + 102400000);   //    400,000 B (NCTR*4)
    unsigned int*   bsum    = (unsigned int*)(ws + 102800000);   //        256 B
    unsigned short* lwT     = (unsigned short*)(ws + 102800256); //  1,310,720 B

    hipLaunchKernelGGL(build_lwT_kernel, dim3((ND * KD) / 256), dim3(256), 0, stream,
                       weights, lwT);
    hipLaunchKernelGGL(zero_u32, dim3((NCTR + 255) / 256), dim3(256), 0, stream, A, NCTR);
    hipLaunchKernelGGL(hist_kernel, dim3(NNZE / 256), dim3(256), 0, stream,
                       conn_rows, A);
    hipLaunchKernelGGL(scan1_kernel, dim3(NBLK), dim3(256), 0, stream, A, bsum);
    hipLaunchKernelGGL(scan2_kernel, dim3(1), dim3(64), 0, stream, bsum);
    hipLaunchKernelGGL(reorder_kernel, dim3(NNZE / 256), dim3(256), 0, stream,
                       conn_rows, conn_vals, conn_cols, A, bsum, entries);
    hipLaunchKernelGGL(accum_lane_kernel, dim3(NB), dim3(256), 0, stream,
                       entries, A, bsum, x, agg);
    hipLaunchKernelGGL(gemm_kernel, dim3((MROWS + 127) / 128, ND / 128), dim3(256),
                       0, stream, agg, lwT, out);
}